// Round 1
// baseline (1047.154 us; speedup 1.0000x reference)
//
#include <hip/hip_runtime.h>
#include <math.h>

#define BB 8
#define SS 1024
#define DD 512
#define HH 8
#define HDIM 64
#define NROWS (BB*SS)          // 8192
#define EPSV 1e-5f
#define MASK_FILL_V -50000.0f
#define SCALE_V 0.125f          // 1/sqrt(64)

// stats[] layout (floats)
#define I_SUM1 0
#define I_SS1  8
#define I_CNT  16
#define I_MEAN1 24
#define I_INV1 32
#define I_SUM2 40
#define I_SS2  48
#define I_MEAN2 56
#define I_INV2 64

// ---------------- stats pass 1: fmask + masked sum/sumsq per batch ----------
__global__ __launch_bounds__(128) void stats1_k(const float* __restrict__ Q,
                                                float* __restrict__ fmask,
                                                float* __restrict__ stats) {
    int row = blockIdx.x;            // 0..8191
    int b = row >> 10;
    int t = threadIdx.x;             // 0..127, 4 floats each (512/row)
    float4 v = *(const float4*)(Q + ((size_t)row << 9) + (t << 2));
    float s  = v.x + v.y + v.z + v.w;
    float ss = v.x*v.x + v.y*v.y + v.z*v.z + v.w*v.w;
    int nz = (v.x != 0.f) || (v.y != 0.f) || (v.z != 0.f) || (v.w != 0.f);
    __shared__ float rs[128], rss[128];
    __shared__ int rnz[128];
    rs[t] = s; rss[t] = ss; rnz[t] = nz;
    __syncthreads();
    for (int off = 64; off > 0; off >>= 1) {
        if (t < off) { rs[t] += rs[t+off]; rss[t] += rss[t+off]; rnz[t] |= rnz[t+off]; }
        __syncthreads();
    }
    if (t == 0) {
        float f = rnz[0] ? 1.f : 0.f;
        fmask[row] = f;
        if (f != 0.f) {
            atomicAdd(&stats[I_SUM1 + b], rs[0]);
            atomicAdd(&stats[I_SS1 + b], rss[0]);
            atomicAdd(&stats[I_CNT + b], 1.f);
        }
    }
}

// ---------------- stats pass 2: masked sum/sumsq of attn_out ----------------
__global__ __launch_bounds__(128) void stats2_k(const float* __restrict__ X,
                                                const float* __restrict__ fmask,
                                                float* __restrict__ stats) {
    int row = blockIdx.x;
    int b = row >> 10;
    int t = threadIdx.x;
    float f = fmask[row];
    float4 v = *(const float4*)(X + ((size_t)row << 9) + (t << 2));
    float s  = (v.x + v.y + v.z + v.w) * f;
    float ss = (v.x*v.x + v.y*v.y + v.z*v.z + v.w*v.w) * f;
    __shared__ float rs[128], rss[128];
    rs[t] = s; rss[t] = ss;
    __syncthreads();
    for (int off = 64; off > 0; off >>= 1) {
        if (t < off) { rs[t] += rs[t+off]; rss[t] += rss[t+off]; }
        __syncthreads();
    }
    if (t == 0 && f != 0.f) {
        atomicAdd(&stats[I_SUM2 + b], rs[0]);
        atomicAdd(&stats[I_SS2 + b], rss[0]);
    }
}

__global__ void finalize_k(float* __restrict__ stats, int osum, int oss, int ocnt,
                           int omean, int oinv) {
    int b = threadIdx.x;
    if (b < BB) {
        float cntD = stats[ocnt + b] * 512.f;
        float mean = stats[osum + b] / cntD;
        float var  = stats[oss + b] / cntD - mean * mean;
        stats[omean + b] = mean;
        stats[oinv + b]  = rsqrtf(var + EPSV);
    }
}

// 4x4 microkernel inner product over a 16-deep K tile
#define GEMM_INNER \
    _Pragma("unroll") \
    for (int kk = 0; kk < 16; ++kk) { \
        const float4 a4 = *(const float4*)&As[kk][ty << 2]; \
        const float4 b4 = *(const float4*)&Bs[kk][tx << 2]; \
        acc[0][0] = fmaf(a4.x, b4.x, acc[0][0]); \
        acc[0][1] = fmaf(a4.x, b4.y, acc[0][1]); \
        acc[0][2] = fmaf(a4.x, b4.z, acc[0][2]); \
        acc[0][3] = fmaf(a4.x, b4.w, acc[0][3]); \
        acc[1][0] = fmaf(a4.y, b4.x, acc[1][0]); \
        acc[1][1] = fmaf(a4.y, b4.y, acc[1][1]); \
        acc[1][2] = fmaf(a4.y, b4.z, acc[1][2]); \
        acc[1][3] = fmaf(a4.y, b4.w, acc[1][3]); \
        acc[2][0] = fmaf(a4.z, b4.x, acc[2][0]); \
        acc[2][1] = fmaf(a4.z, b4.y, acc[2][1]); \
        acc[2][2] = fmaf(a4.z, b4.z, acc[2][2]); \
        acc[2][3] = fmaf(a4.z, b4.w, acc[2][3]); \
        acc[3][0] = fmaf(a4.w, b4.x, acc[3][0]); \
        acc[3][1] = fmaf(a4.w, b4.y, acc[3][1]); \
        acc[3][2] = fmaf(a4.w, b4.z, acc[3][2]); \
        acc[3][3] = fmaf(a4.w, b4.w, acc[3][3]); \
    }

// ---------------- fused set_norm + QKV projection GEMM ----------------------
// C = (norm(Q) @ W + bias) * fmask ; z selects Wq/Wk/Wv
__global__ __launch_bounds__(256) void proj_gemm(
    const float* __restrict__ Q, const float* __restrict__ stats,
    const float* __restrict__ fmask,
    const float* __restrict__ Wq, const float* __restrict__ bq,
    const float* __restrict__ Wk, const float* __restrict__ bk,
    const float* __restrict__ Wv, const float* __restrict__ bv,
    float* __restrict__ Qp, float* __restrict__ Kp, float* __restrict__ Vp)
{
    int z = blockIdx.z;
    const float* W    = (z == 0) ? Wq : (z == 1) ? Wk : Wv;
    const float* bias = (z == 0) ? bq : (z == 1) ? bk : bv;
    float* C          = (z == 0) ? Qp : (z == 1) ? Kp : Vp;
    __shared__ float As[16][68];
    __shared__ float Bs[16][68];
    int t = threadIdx.x;
    int tx = t & 15, ty = t >> 4;
    int m0 = blockIdx.y << 6, n0 = blockIdx.x << 6;
    int ary = t >> 2, akk = (t & 3) << 2;     // A tile: 64 rows x 16 k
    int bkk = t >> 4, brx = (t & 15) << 2;    // B tile: 16 k x 64 n
    int arow = m0 + ary;
    int ab = arow >> 10;
    float fi   = fmask[arow] * stats[I_INV1 + ab];
    float mean = stats[I_MEAN1 + ab];
    float acc[4][4] = {};
    for (int k0 = 0; k0 < 512; k0 += 16) {
        float4 av = *(const float4*)(Q + ((size_t)arow << 9) + k0 + akk);
        As[akk+0][ary] = (av.x - mean) * fi;
        As[akk+1][ary] = (av.y - mean) * fi;
        As[akk+2][ary] = (av.z - mean) * fi;
        As[akk+3][ary] = (av.w - mean) * fi;
        float4 bv4 = *(const float4*)(W + ((size_t)(k0 + bkk) << 9) + n0 + brx);
        *(float4*)&Bs[bkk][brx] = bv4;
        __syncthreads();
        GEMM_INNER
        __syncthreads();
    }
    float4 bias4 = *(const float4*)(bias + n0 + (tx << 2));
    #pragma unroll
    for (int i = 0; i < 4; ++i) {
        int m = m0 + (ty << 2) + i;
        float fm = fmask[m];
        float4 o;
        o.x = (acc[i][0] + bias4.x) * fm;
        o.y = (acc[i][1] + bias4.y) * fm;
        o.z = (acc[i][2] + bias4.z) * fm;
        o.w = (acc[i][3] + bias4.w) * fm;
        *(float4*)(C + ((size_t)m << 9) + n0 + (tx << 2)) = o;
    }
}

// ---------------- scores = q @ k^T * scale + mask ---------------------------
__global__ __launch_bounds__(256) void scores_gemm(
    const float* __restrict__ Qp, const float* __restrict__ Kp,
    const float* __restrict__ fmask, float* __restrict__ w)
{
    int bh = blockIdx.z;                 // 0..63
    int b = bh >> 3, h = bh & 7;
    const float* A  = Qp + ((size_t)b << 19) + (h << 6);
    const float* Bm = Kp + ((size_t)b << 19) + (h << 6);
    __shared__ float As[16][68];
    __shared__ float Bs[16][68];
    int t = threadIdx.x, tx = t & 15, ty = t >> 4;
    int q0 = blockIdx.y << 6, k0c = blockIdx.x << 6;
    int ary = t >> 2, akk = (t & 3) << 2;
    float acc[4][4] = {};
    for (int kt = 0; kt < 64; kt += 16) {
        float4 av = *(const float4*)(A + ((size_t)(q0 + ary) << 9) + kt + akk);
        As[akk+0][ary] = av.x; As[akk+1][ary] = av.y;
        As[akk+2][ary] = av.z; As[akk+3][ary] = av.w;
        float4 bv4 = *(const float4*)(Bm + ((size_t)(k0c + ary) << 9) + kt + akk);
        Bs[akk+0][ary] = bv4.x; Bs[akk+1][ary] = bv4.y;
        Bs[akk+2][ary] = bv4.z; Bs[akk+3][ary] = bv4.w;
        __syncthreads();
        GEMM_INNER
        __syncthreads();
    }
    float4 fk4 = *(const float4*)(fmask + (b << 10) + k0c + (tx << 2));
    size_t wbase = ((size_t)bh << 20);
    #pragma unroll
    for (int i = 0; i < 4; ++i) {
        int q = q0 + (ty << 2) + i;
        float fq = fmask[(b << 10) + q];
        float4 o;
        o.x = acc[i][0] * SCALE_V + ((fq * fk4.x) != 0.f ? 0.f : MASK_FILL_V);
        o.y = acc[i][1] * SCALE_V + ((fq * fk4.y) != 0.f ? 0.f : MASK_FILL_V);
        o.z = acc[i][2] * SCALE_V + ((fq * fk4.z) != 0.f ? 0.f : MASK_FILL_V);
        o.w = acc[i][3] * SCALE_V + ((fq * fk4.w) != 0.f ? 0.f : MASK_FILL_V);
        *(float4*)(w + wbase + ((size_t)q << 10) + k0c + (tx << 2)) = o;
    }
}

// ---------------- row softmax (in place on w) -------------------------------
__global__ __launch_bounds__(256) void softmax_k(const float* __restrict__ fmask,
                                                 float* __restrict__ w) {
    int r = blockIdx.x;                  // 0..65535 = (b,h,q)
    int b = r >> 13;
    int q = r & 1023;
    int t = threadIdx.x;
    size_t base = (size_t)r << 10;
    float fq = fmask[(b << 10) + q];
    float4 v = *(const float4*)(w + base + (t << 2));
    __shared__ float red[256];
    if (fq == 0.f) {                     // uniform per block: no divergence issue
        float4 z = {0.f, 0.f, 0.f, 0.f};
        *(float4*)(w + base + (t << 2)) = z;
        return;
    }
    float m = fmaxf(fmaxf(v.x, v.y), fmaxf(v.z, v.w));
    red[t] = m; __syncthreads();
    for (int off = 128; off > 0; off >>= 1) {
        if (t < off) red[t] = fmaxf(red[t], red[t + off]);
        __syncthreads();
    }
    m = red[0]; __syncthreads();
    float4 e;
    e.x = __expf(v.x - m); e.y = __expf(v.y - m);
    e.z = __expf(v.z - m); e.w = __expf(v.w - m);
    red[t] = e.x + e.y + e.z + e.w; __syncthreads();
    for (int off = 128; off > 0; off >>= 1) {
        if (t < off) red[t] += red[t + off];
        __syncthreads();
    }
    float rinv = 1.f / red[0];
    float4 km = *(const float4*)(fmask + (b << 10) + (t << 2));
    float4 o;
    o.x = e.x * rinv * km.x; o.y = e.y * rinv * km.y;
    o.z = e.z * rinv * km.z; o.w = e.w * rinv * km.w;
    *(float4*)(w + base + (t << 2)) = o;
}

// ---------------- attn = w @ v ; fused +Q residual --------------------------
__global__ __launch_bounds__(256) void pv_gemm(
    const float* __restrict__ w, const float* __restrict__ Vp,
    const float* __restrict__ Q, float* __restrict__ attn)
{
    int bh = blockIdx.y;                 // 0..63
    int b = bh >> 3, h = bh & 7;
    const float* A  = w + ((size_t)bh << 20);
    const float* Bv = Vp + ((size_t)b << 19) + (h << 6);
    __shared__ float As[16][68];
    __shared__ float Bs[16][68];
    int t = threadIdx.x, tx = t & 15, ty = t >> 4;
    int q0 = blockIdx.x << 6;
    int ary = t >> 2, akk = (t & 3) << 2;
    int bkk = t >> 4, brx = (t & 15) << 2;
    float acc[4][4] = {};
    for (int k0 = 0; k0 < 1024; k0 += 16) {
        float4 av = *(const float4*)(A + ((size_t)(q0 + ary) << 10) + k0 + akk);
        As[akk+0][ary] = av.x; As[akk+1][ary] = av.y;
        As[akk+2][ary] = av.z; As[akk+3][ary] = av.w;
        float4 bv4 = *(const float4*)(Bv + ((size_t)(k0 + bkk) << 9) + brx);
        *(float4*)&Bs[bkk][brx] = bv4;
        __syncthreads();
        GEMM_INNER
        __syncthreads();
    }
    #pragma unroll
    for (int i = 0; i < 4; ++i) {
        int q = q0 + (ty << 2) + i;
        size_t off = ((size_t)((b << 10) + q) << 9) + (h << 6) + (tx << 2);
        float4 qv = *(const float4*)(Q + off);
        float4 o;
        o.x = acc[i][0] + qv.x; o.y = acc[i][1] + qv.y;
        o.z = acc[i][2] + qv.z; o.w = acc[i][3] + qv.w;
        *(float4*)(attn + off) = o;
    }
}

// ---------------- out = attn_out + relu(norm2(attn_out) @ Wo + bo) ----------
__global__ __launch_bounds__(256) void final_gemm(
    const float* __restrict__ attn, const float* __restrict__ stats,
    const float* __restrict__ fmask,
    const float* __restrict__ Wo, const float* __restrict__ bo,
    float* __restrict__ out)
{
    __shared__ float As[16][68];
    __shared__ float Bs[16][68];
    int t = threadIdx.x, tx = t & 15, ty = t >> 4;
    int m0 = blockIdx.y << 6, n0 = blockIdx.x << 6;
    int ary = t >> 2, akk = (t & 3) << 2;
    int bkk = t >> 4, brx = (t & 15) << 2;
    int arow = m0 + ary, ab = arow >> 10;
    float fi   = fmask[arow] * stats[I_INV2 + ab];
    float mean = stats[I_MEAN2 + ab];
    float acc[4][4] = {};
    for (int k0 = 0; k0 < 512; k0 += 16) {
        float4 av = *(const float4*)(attn + ((size_t)arow << 9) + k0 + akk);
        As[akk+0][ary] = (av.x - mean) * fi;
        As[akk+1][ary] = (av.y - mean) * fi;
        As[akk+2][ary] = (av.z - mean) * fi;
        As[akk+3][ary] = (av.w - mean) * fi;
        float4 bv4 = *(const float4*)(Wo + ((size_t)(k0 + bkk) << 9) + n0 + brx);
        *(float4*)&Bs[bkk][brx] = bv4;
        __syncthreads();
        GEMM_INNER
        __syncthreads();
    }
    float4 bo4 = *(const float4*)(bo + n0 + (tx << 2));
    #pragma unroll
    for (int i = 0; i < 4; ++i) {
        int m = m0 + (ty << 2) + i;
        size_t off = ((size_t)m << 9) + n0 + (tx << 2);
        float4 ao = *(const float4*)(attn + off);
        float4 o;
        o.x = ao.x + fmaxf(acc[i][0] + bo4.x, 0.f);
        o.y = ao.y + fmaxf(acc[i][1] + bo4.y, 0.f);
        o.z = ao.z + fmaxf(acc[i][2] + bo4.z, 0.f);
        o.w = ao.w + fmaxf(acc[i][3] + bo4.w, 0.f);
        *(float4*)(out + off) = o;
    }
}

extern "C" void kernel_launch(void* const* d_in, const int* in_sizes, int n_in,
                              void* d_out, int out_size, void* d_ws, size_t ws_size,
                              hipStream_t stream) {
    const float* Q  = (const float*)d_in[0];
    const float* Wq = (const float*)d_in[1];
    const float* bq = (const float*)d_in[2];
    const float* Wk = (const float*)d_in[3];
    const float* bk = (const float*)d_in[4];
    const float* Wv = (const float*)d_in[5];
    const float* bv = (const float*)d_in[6];
    const float* Wo = (const float*)d_in[7];
    const float* bo = (const float*)d_in[8];
    float* out = (float*)d_out;                       // (B,S,D) = 4194304 floats
    float* w   = out + (size_t)BB * SS * DD;          // (B,H,S,S) = 67108864 floats

    char* ws = (char*)d_ws;
    float* stats = (float*)ws;                        // 1 KB
    float* fmask = (float*)(ws + 4096);               // 8192 floats
    float* Qp    = (float*)(ws + (1 << 16));          // each 16 MB
    float* Kp    = Qp + (size_t)NROWS * DD;
    float* Vp    = Kp + (size_t)NROWS * DD;
    float* attn  = Vp + (size_t)NROWS * DD;           // total ws ~64.1 MB

    hipMemsetAsync(stats, 0, 1024, stream);
    stats1_k<<<NROWS, 128, 0, stream>>>(Q, fmask, stats);
    finalize_k<<<1, 64, 0, stream>>>(stats, I_SUM1, I_SS1, I_CNT, I_MEAN1, I_INV1);
    proj_gemm<<<dim3(8, 128, 3), 256, 0, stream>>>(Q, stats, fmask,
                                                   Wq, bq, Wk, bk, Wv, bv,
                                                   Qp, Kp, Vp);
    scores_gemm<<<dim3(16, 16, 64), 256, 0, stream>>>(Qp, Kp, fmask, w);
    softmax_k<<<BB * HH * SS, 256, 0, stream>>>(fmask, w);
    pv_gemm<<<dim3(16, 64), 256, 0, stream>>>(w, Vp, Q, attn);
    stats2_k<<<NROWS, 128, 0, stream>>>(attn, fmask, stats);
    finalize_k<<<1, 64, 0, stream>>>(stats, I_SUM2, I_SS2, I_CNT, I_MEAN2, I_INV2);
    final_gemm<<<dim3(8, 128), 256, 0, stream>>>(attn, stats, fmask, Wo, bo, out);
}

// Round 2
// 791.645 us; speedup vs baseline: 1.3228x; 1.3228x over previous
//
#include <hip/hip_runtime.h>
#include <math.h>

#define BB 8
#define SS 1024
#define DD 512
#define HH 8
#define NROWS (BB*SS)          // 8192
#define EPSV 1e-5f
#define SCALE_V 0.125f          // 1/sqrt(64)

// stats[] layout (floats)
#define I_SUM1 0
#define I_SS1  8
#define I_CNT  16
#define I_MEAN1 24
#define I_INV1 32
#define I_SUM2 40
#define I_SS2  48
#define I_MEAN2 56
#define I_INV2 64

typedef __bf16 bf16x8 __attribute__((ext_vector_type(8)));
typedef __bf16 bf16x4 __attribute__((ext_vector_type(4)));
typedef float f32x4 __attribute__((ext_vector_type(4)));

#define MFMA16(a,b,c) __builtin_amdgcn_mfma_f32_16x16x32_bf16(a,b,c,0,0,0)

// LDS tiles: 64 rows x 32 k bf16, row padded to 40 elems (80 B, 16B-aligned, 2-way bank alias = free)
#define LDSTRIDE 40

// MFMA inner step: wave computes 16(m) x 64(n); 4 accumulators
#define DO_MFMA() do { \
    bf16x8 af = *(const bf16x8*)&As[aoff]; \
    acc[0] = MFMA16(af, *(const bf16x8*)&Bs[boff0       ], acc[0]); \
    acc[1] = MFMA16(af, *(const bf16x8*)&Bs[boff0 +  640], acc[1]); \
    acc[2] = MFMA16(af, *(const bf16x8*)&Bs[boff0 + 1280], acc[2]); \
    acc[3] = MFMA16(af, *(const bf16x8*)&Bs[boff0 + 1920], acc[3]); \
} while (0)

// ---------------- stats pass 1: fmask + masked sum/sumsq per batch ----------
__global__ __launch_bounds__(128) void stats1_k(const float* __restrict__ Q,
                                                float* __restrict__ fmask,
                                                float* __restrict__ stats) {
    int row = blockIdx.x;            // 0..8191
    int b = row >> 10;
    int t = threadIdx.x;             // 0..127, 4 floats each (512/row)
    float4 v = *(const float4*)(Q + ((size_t)row << 9) + (t << 2));
    float s  = v.x + v.y + v.z + v.w;
    float ss = v.x*v.x + v.y*v.y + v.z*v.z + v.w*v.w;
    int nz = (v.x != 0.f) || (v.y != 0.f) || (v.z != 0.f) || (v.w != 0.f);
    __shared__ float rs[128], rss[128];
    __shared__ int rnz[128];
    rs[t] = s; rss[t] = ss; rnz[t] = nz;
    __syncthreads();
    for (int off = 64; off > 0; off >>= 1) {
        if (t < off) { rs[t] += rs[t+off]; rss[t] += rss[t+off]; rnz[t] |= rnz[t+off]; }
        __syncthreads();
    }
    if (t == 0) {
        float f = rnz[0] ? 1.f : 0.f;
        fmask[row] = f;
        if (f != 0.f) {
            atomicAdd(&stats[I_SUM1 + b], rs[0]);
            atomicAdd(&stats[I_SS1 + b], rss[0]);
            atomicAdd(&stats[I_CNT + b], 1.f);
        }
    }
}

// ---------------- stats pass 2: masked sum/sumsq of attn_out ----------------
__global__ __launch_bounds__(128) void stats2_k(const float* __restrict__ X,
                                                const float* __restrict__ fmask,
                                                float* __restrict__ stats) {
    int row = blockIdx.x;
    int b = row >> 10;
    int t = threadIdx.x;
    float f = fmask[row];
    float4 v = *(const float4*)(X + ((size_t)row << 9) + (t << 2));
    float s  = (v.x + v.y + v.z + v.w) * f;
    float ss = (v.x*v.x + v.y*v.y + v.z*v.z + v.w*v.w) * f;
    __shared__ float rs[128], rss[128];
    rs[t] = s; rss[t] = ss;
    __syncthreads();
    for (int off = 64; off > 0; off >>= 1) {
        if (t < off) { rs[t] += rs[t+off]; rss[t] += rss[t+off]; }
        __syncthreads();
    }
    if (t == 0 && f != 0.f) {
        atomicAdd(&stats[I_SUM2 + b], rs[0]);
        atomicAdd(&stats[I_SS2 + b], rss[0]);
    }
}

__global__ void finalize_k(float* __restrict__ stats, int osum, int oss, int ocnt,
                           int omean, int oinv) {
    int b = threadIdx.x;
    if (b < BB) {
        float cntD = stats[ocnt + b] * 512.f;
        float mean = stats[osum + b] / cntD;
        float var  = stats[oss + b] / cntD - mean * mean;
        stats[omean + b] = mean;
        stats[oinv + b]  = rsqrtf(var + EPSV);
    }
}

// ---------------- transpose+cast weights: W[k][n] fp32 -> Wt[n][k] bf16 -----
__global__ __launch_bounds__(256) void tw_k(const float* __restrict__ Wq,
                                            const float* __restrict__ Wk,
                                            const float* __restrict__ Wv,
                                            const float* __restrict__ Wo,
                                            __bf16* __restrict__ Wt) {
    int z = blockIdx.z;
    const float* W = (z == 0) ? Wq : (z == 1) ? Wk : (z == 2) ? Wv : Wo;
    __bf16* dst = Wt + ((size_t)z << 18);
    __shared__ float tile[64][65];
    int t = threadIdx.x;
    int k0 = blockIdx.y << 6, n0 = blockIdx.x << 6;
    int r = t >> 4, c = (t & 15) << 2;
    #pragma unroll
    for (int i = 0; i < 4; ++i) {
        float4 v = *(const float4*)(W + (size_t)(k0 + r + i*16) * 512 + n0 + c);
        tile[r + i*16][c+0] = v.x; tile[r + i*16][c+1] = v.y;
        tile[r + i*16][c+2] = v.z; tile[r + i*16][c+3] = v.w;
    }
    __syncthreads();
    #pragma unroll
    for (int i = 0; i < 4; ++i) {
        int n = r + i*16;
        bf16x4 o;
        o[0] = (__bf16)tile[c+0][n]; o[1] = (__bf16)tile[c+1][n];
        o[2] = (__bf16)tile[c+2][n]; o[3] = (__bf16)tile[c+3][n];
        *(bf16x4*)(dst + (size_t)(n0 + n) * 512 + k0 + c) = o;
    }
}

// ---------------- transpose Vp bf16 [s][h*64+d] -> Vt bf16 [bh][d][s] -------
__global__ __launch_bounds__(256) void tv_k(const __bf16* __restrict__ Vp,
                                            __bf16* __restrict__ Vt) {
    int bh = blockIdx.y; int b = bh >> 3, h = bh & 7;
    int s0 = blockIdx.x << 6;
    __shared__ __bf16 tile[64][68];
    int t = threadIdx.x;
    int r = t >> 4, c = (t & 15) << 2;
    #pragma unroll
    for (int i = 0; i < 4; ++i) {
        bf16x4 v = *(const bf16x4*)(Vp + ((size_t)((b << 10) + s0 + r + i*16) << 9) + (h << 6) + c);
        tile[r + i*16][c+0] = v[0]; tile[r + i*16][c+1] = v[1];
        tile[r + i*16][c+2] = v[2]; tile[r + i*16][c+3] = v[3];
    }
    __syncthreads();
    #pragma unroll
    for (int i = 0; i < 4; ++i) {
        int d = r + i*16;
        bf16x4 o;
        o[0] = tile[c+0][d]; o[1] = tile[c+1][d];
        o[2] = tile[c+2][d]; o[3] = tile[c+3][d];
        *(bf16x4*)(Vt + ((size_t)bh << 16) + ((size_t)d << 10) + s0 + c) = o;
    }
}

// ---------------- fused set_norm + QKV projection (MFMA) --------------------
__global__ __launch_bounds__(256) void proj_gemm(
    const float* __restrict__ Q, const float* __restrict__ stats,
    const float* __restrict__ fmask, const __bf16* __restrict__ Wt,
    const float* __restrict__ bq, const float* __restrict__ bk,
    const float* __restrict__ bv,
    __bf16* __restrict__ Qp, __bf16* __restrict__ Kp, __bf16* __restrict__ Vp)
{
    int z = blockIdx.z;
    const __bf16* W = Wt + ((size_t)z << 18);
    const float* bias = (z == 0) ? bq : (z == 1) ? bk : bv;
    __bf16* C = (z == 0) ? Qp : (z == 1) ? Kp : Vp;
    __shared__ __align__(16) __bf16 As[64 * LDSTRIDE];
    __shared__ __align__(16) __bf16 Bs[64 * LDSTRIDE];
    int t = threadIdx.x;
    int srow = t >> 2, skp = (t & 3) << 3;
    int m0 = blockIdx.y << 6, n0 = blockIdx.x << 6;
    int arow = m0 + srow, ab = arow >> 10;
    float fi   = fmask[arow] * stats[I_INV1 + ab];
    float mean = stats[I_MEAN1 + ab];
    int wave = t >> 6, lane = t & 63, quad = lane >> 4, l16 = lane & 15;
    int aoff  = (wave * 16 + l16) * LDSTRIDE + quad * 8;
    int boff0 = l16 * LDSTRIDE + quad * 8;
    f32x4 acc[4] = {};
    const float*  Arow = Q + ((size_t)arow << 9);
    const __bf16* Brow = W + ((size_t)(n0 + srow) << 9);
    for (int k0 = 0; k0 < 512; k0 += 32) {
        float4 a0 = *(const float4*)(Arow + k0 + skp);
        float4 a1 = *(const float4*)(Arow + k0 + skp + 4);
        bf16x8 av;
        av[0] = (__bf16)((a0.x - mean) * fi); av[1] = (__bf16)((a0.y - mean) * fi);
        av[2] = (__bf16)((a0.z - mean) * fi); av[3] = (__bf16)((a0.w - mean) * fi);
        av[4] = (__bf16)((a1.x - mean) * fi); av[5] = (__bf16)((a1.y - mean) * fi);
        av[6] = (__bf16)((a1.z - mean) * fi); av[7] = (__bf16)((a1.w - mean) * fi);
        *(bf16x8*)&As[srow * LDSTRIDE + skp] = av;
        *(bf16x8*)&Bs[srow * LDSTRIDE + skp] = *(const bf16x8*)(Brow + k0 + skp);
        __syncthreads();
        DO_MFMA();
        __syncthreads();
    }
    #pragma unroll
    for (int nt = 0; nt < 4; ++nt) {
        int n = n0 + nt * 16 + l16;
        float bn = bias[n];
        #pragma unroll
        for (int reg = 0; reg < 4; ++reg) {
            int m = m0 + wave * 16 + quad * 4 + reg;
            C[((size_t)m << 9) + n] = (__bf16)((acc[nt][reg] + bn) * fmask[m]);
        }
    }
}

// ---------------- scores: e = exp(q.k*scale) (masked->0), rowsum atomics ----
__global__ __launch_bounds__(256) void scores_k(
    const __bf16* __restrict__ Qp, const __bf16* __restrict__ Kp,
    const float* __restrict__ fmask, float* __restrict__ w,
    float* __restrict__ rowsum)
{
    int bh = blockIdx.z, b = bh >> 3, h = bh & 7;
    int kc0 = blockIdx.x << 6, q0 = blockIdx.y << 6;
    __shared__ __align__(16) __bf16 As[64 * LDSTRIDE];
    __shared__ __align__(16) __bf16 Bs[64 * LDSTRIDE];
    int t = threadIdx.x;
    int srow = t >> 2, skp = (t & 3) << 3;
    int wave = t >> 6, lane = t & 63, quad = lane >> 4, l16 = lane & 15;
    int aoff  = (wave * 16 + l16) * LDSTRIDE + quad * 8;
    int boff0 = l16 * LDSTRIDE + quad * 8;
    f32x4 acc[4] = {};
    const __bf16* Abase = Qp + ((size_t)((b << 10) + q0  + srow) << 9) + (h << 6);
    const __bf16* Bbase = Kp + ((size_t)((b << 10) + kc0 + srow) << 9) + (h << 6);
    for (int k0 = 0; k0 < 64; k0 += 32) {
        *(bf16x8*)&As[srow * LDSTRIDE + skp] = *(const bf16x8*)(Abase + k0 + skp);
        *(bf16x8*)&Bs[srow * LDSTRIDE + skp] = *(const bf16x8*)(Bbase + k0 + skp);
        __syncthreads();
        DO_MFMA();
        __syncthreads();
    }
    size_t wbase = ((size_t)bh << 20);
    float rsum[4] = {0.f, 0.f, 0.f, 0.f};
    #pragma unroll
    for (int nt = 0; nt < 4; ++nt) {
        int kc = kc0 + nt * 16 + l16;
        float fk = fmask[(b << 10) + kc];
        #pragma unroll
        for (int reg = 0; reg < 4; ++reg) {
            int q = q0 + wave * 16 + quad * 4 + reg;
            float fq = fmask[(b << 10) + q];
            float e = (fq * fk != 0.f) ? __expf(acc[nt][reg] * SCALE_V) : 0.f;
            w[wbase + ((size_t)q << 10) + kc] = e;
            rsum[reg] += e;
        }
    }
    #pragma unroll
    for (int reg = 0; reg < 4; ++reg) {
        float v = rsum[reg];
        v += __shfl_xor(v, 1); v += __shfl_xor(v, 2);
        v += __shfl_xor(v, 4); v += __shfl_xor(v, 8);
        if (l16 == 0) {
            int q = q0 + wave * 16 + quad * 4 + reg;
            atomicAdd(&rowsum[(bh << 10) + q], v);
        }
    }
}

// ---------------- pv: normalize w in place, attn = w @ v + Q ----------------
__global__ __launch_bounds__(256) void pv_k(
    float* __restrict__ w, const float* __restrict__ rowsum,
    const __bf16* __restrict__ Vt, const float* __restrict__ Q,
    float* __restrict__ attn)
{
    int bh = blockIdx.y, b = bh >> 3, h = bh & 7;
    int q0 = blockIdx.x << 6;
    __shared__ __align__(16) __bf16 As[64 * LDSTRIDE];
    __shared__ __align__(16) __bf16 Bs[64 * LDSTRIDE];
    int t = threadIdx.x;
    int srow = t >> 2, skp = (t & 3) << 3;
    int wave = t >> 6, lane = t & 63, quad = lane >> 4, l16 = lane & 15;
    int aoff  = (wave * 16 + l16) * LDSTRIDE + quad * 8;
    int boff0 = l16 * LDSTRIDE + quad * 8;
    f32x4 acc[4] = {};
    int qrow = q0 + srow;
    float rs = rowsum[(bh << 10) + qrow];
    float inv = rs > 0.f ? 1.f / rs : 0.f;
    float* Wr = w + ((size_t)bh << 20) + ((size_t)qrow << 10);
    const __bf16* Vb = Vt + ((size_t)bh << 16) + ((size_t)srow << 10);
    for (int k0 = 0; k0 < 1024; k0 += 32) {
        float4 e0 = *(const float4*)(Wr + k0 + skp);
        float4 e1 = *(const float4*)(Wr + k0 + skp + 4);
        e0.x *= inv; e0.y *= inv; e0.z *= inv; e0.w *= inv;
        e1.x *= inv; e1.y *= inv; e1.z *= inv; e1.w *= inv;
        *(float4*)(Wr + k0 + skp)     = e0;
        *(float4*)(Wr + k0 + skp + 4) = e1;
        bf16x8 av;
        av[0] = (__bf16)e0.x; av[1] = (__bf16)e0.y; av[2] = (__bf16)e0.z; av[3] = (__bf16)e0.w;
        av[4] = (__bf16)e1.x; av[5] = (__bf16)e1.y; av[6] = (__bf16)e1.z; av[7] = (__bf16)e1.w;
        *(bf16x8*)&As[srow * LDSTRIDE + skp] = av;
        *(bf16x8*)&Bs[srow * LDSTRIDE + skp] = *(const bf16x8*)(Vb + k0 + skp);
        __syncthreads();
        DO_MFMA();
        __syncthreads();
    }
    #pragma unroll
    for (int nt = 0; nt < 4; ++nt) {
        int d = nt * 16 + l16;
        #pragma unroll
        for (int reg = 0; reg < 4; ++reg) {
            int q = q0 + wave * 16 + quad * 4 + reg;
            size_t off = ((size_t)((b << 10) + q) << 9) + (h << 6) + d;
            attn[off] = acc[nt][reg] + Q[off];
        }
    }
}

// ---------------- out = attn + relu(norm2(attn) @ Wo + bo) ------------------
__global__ __launch_bounds__(256) void final_gemm(
    const float* __restrict__ attn, const float* __restrict__ stats,
    const float* __restrict__ fmask, const __bf16* __restrict__ Wot,
    const float* __restrict__ bo, float* __restrict__ out)
{
    __shared__ __align__(16) __bf16 As[64 * LDSTRIDE];
    __shared__ __align__(16) __bf16 Bs[64 * LDSTRIDE];
    int t = threadIdx.x;
    int srow = t >> 2, skp = (t & 3) << 3;
    int m0 = blockIdx.y << 6, n0 = blockIdx.x << 6;
    int arow = m0 + srow, ab = arow >> 10;
    float fi   = fmask[arow] * stats[I_INV2 + ab];
    float mean = stats[I_MEAN2 + ab];
    int wave = t >> 6, lane = t & 63, quad = lane >> 4, l16 = lane & 15;
    int aoff  = (wave * 16 + l16) * LDSTRIDE + quad * 8;
    int boff0 = l16 * LDSTRIDE + quad * 8;
    f32x4 acc[4] = {};
    const float*  Arow = attn + ((size_t)arow << 9);
    const __bf16* Brow = Wot + ((size_t)(n0 + srow) << 9);
    for (int k0 = 0; k0 < 512; k0 += 32) {
        float4 a0 = *(const float4*)(Arow + k0 + skp);
        float4 a1 = *(const float4*)(Arow + k0 + skp + 4);
        bf16x8 av;
        av[0] = (__bf16)((a0.x - mean) * fi); av[1] = (__bf16)((a0.y - mean) * fi);
        av[2] = (__bf16)((a0.z - mean) * fi); av[3] = (__bf16)((a0.w - mean) * fi);
        av[4] = (__bf16)((a1.x - mean) * fi); av[5] = (__bf16)((a1.y - mean) * fi);
        av[6] = (__bf16)((a1.z - mean) * fi); av[7] = (__bf16)((a1.w - mean) * fi);
        *(bf16x8*)&As[srow * LDSTRIDE + skp] = av;
        *(bf16x8*)&Bs[srow * LDSTRIDE + skp] = *(const bf16x8*)(Brow + k0 + skp);
        __syncthreads();
        DO_MFMA();
        __syncthreads();
    }
    #pragma unroll
    for (int nt = 0; nt < 4; ++nt) {
        int n = n0 + nt * 16 + l16;
        float bn = bo[n];
        #pragma unroll
        for (int reg = 0; reg < 4; ++reg) {
            int m = m0 + wave * 16 + quad * 4 + reg;
            size_t off = ((size_t)m << 9) + n;
            out[off] = attn[off] + fmaxf(acc[nt][reg] + bn, 0.f);
        }
    }
}

extern "C" void kernel_launch(void* const* d_in, const int* in_sizes, int n_in,
                              void* d_out, int out_size, void* d_ws, size_t ws_size,
                              hipStream_t stream) {
    const float* Q  = (const float*)d_in[0];
    const float* Wq = (const float*)d_in[1];
    const float* bq = (const float*)d_in[2];
    const float* Wk = (const float*)d_in[3];
    const float* bk = (const float*)d_in[4];
    const float* Wv = (const float*)d_in[5];
    const float* bv = (const float*)d_in[6];
    const float* Wo = (const float*)d_in[7];
    const float* bo = (const float*)d_in[8];
    float* out = (float*)d_out;                       // (B,S,D) = 4194304 floats
    float* w   = out + (size_t)BB * SS * DD;          // (B,H,S,S) = 67108864 floats

    char* ws = (char*)d_ws;
    float* stats  = (float*)ws;                       // 1 KB (4 KB reserved)
    float* rowsum = (float*)(ws + 4096);              // 64*1024 fp32 = 256 KB
    float* fmask  = (float*)(ws + 4096 + 262144);     // 32 KB
    __bf16* Wt = (__bf16*)(ws + 327680);              // 4 x 512x512 bf16 = 2 MB
    __bf16* Qp = Wt + ((size_t)4 << 18);              // each 8192x512 bf16 = 8 MB
    __bf16* Kp = Qp + ((size_t)NROWS * DD);
    __bf16* Vp = Kp + ((size_t)NROWS * DD);
    __bf16* Vt = Vp + ((size_t)NROWS * DD);           // [bh][64][1024] bf16 = 8 MB
    float* attn = (float*)(Vt + ((size_t)NROWS * DD)); // 16 MB fp32; total ~51 MB

    hipMemsetAsync(ws, 0, 4096 + 262144, stream);     // stats + rowsum
    stats1_k<<<NROWS, 128, 0, stream>>>(Q, fmask, stats);
    finalize_k<<<1, 64, 0, stream>>>(stats, I_SUM1, I_SS1, I_CNT, I_MEAN1, I_INV1);
    tw_k<<<dim3(8, 8, 4), 256, 0, stream>>>(Wq, Wk, Wv, Wo, Wt);
    proj_gemm<<<dim3(8, 128, 3), 256, 0, stream>>>(Q, stats, fmask, Wt,
                                                   bq, bk, bv, Qp, Kp, Vp);
    tv_k<<<dim3(16, 64), 256, 0, stream>>>(Vp, Vt);
    scores_k<<<dim3(16, 16, 64), 256, 0, stream>>>(Qp, Kp, fmask, w, rowsum);
    pv_k<<<dim3(16, 64), 256, 0, stream>>>(w, rowsum, Vt, Q, attn);
    stats2_k<<<NROWS, 128, 0, stream>>>(attn, fmask, stats);
    finalize_k<<<1, 64, 0, stream>>>(stats, I_SUM2, I_SS2, I_CNT, I_MEAN2, I_INV2);
    final_gemm<<<dim3(8, 128), 256, 0, stream>>>(attn, stats, fmask,
                                                 Wt + ((size_t)3 << 18), bo, out);
}

// Round 4
// 740.331 us; speedup vs baseline: 1.4144x; 1.0693x over previous
//
#include <hip/hip_runtime.h>
#include <math.h>

#define BB 8
#define SS 1024
#define DD 512
#define HH 8
#define NROWS (BB*SS)          // 8192
#define EPSV 1e-5f
#define SCALE_V 0.125f          // 1/sqrt(64)

// stats[] layout (floats)
#define I_SUM1 0
#define I_SS1  8
#define I_CNT  16
#define I_MEAN1 24
#define I_INV1 32
#define I_SUM2 40
#define I_SS2  48
#define I_MEAN2 56
#define I_INV2 64

typedef __bf16 bf16x8 __attribute__((ext_vector_type(8)));
typedef __bf16 bf16x4 __attribute__((ext_vector_type(4)));
typedef float f32x4 __attribute__((ext_vector_type(4)));

#define MFMA16(a,b,c) __builtin_amdgcn_mfma_f32_16x16x32_bf16(a,b,c,0,0,0)

// GEMM LDS tiles: 64 rows x 32 k bf16, padded stride 40 (2-way bank alias = free)
#define LDSTRIDE 40

#define DO_MFMA() do { \
    bf16x8 af = *(const bf16x8*)&As[aoff]; \
    acc[0] = MFMA16(af, *(const bf16x8*)&Bs[boff0       ], acc[0]); \
    acc[1] = MFMA16(af, *(const bf16x8*)&Bs[boff0 +  640], acc[1]); \
    acc[2] = MFMA16(af, *(const bf16x8*)&Bs[boff0 + 1280], acc[2]); \
    acc[3] = MFMA16(af, *(const bf16x8*)&Bs[boff0 + 1920], acc[3]); \
} while (0)

// attention tiles: 64 rows x 64 k bf16, padded stride 72
#define ASTR 72

// ---------------- stats pass 1: fmask + masked sum/sumsq per batch ----------
__global__ __launch_bounds__(128) void stats1_k(const float* __restrict__ Q,
                                                float* __restrict__ fmask,
                                                float* __restrict__ stats) {
    int row = blockIdx.x;
    int b = row >> 10;
    int t = threadIdx.x;
    float4 v = *(const float4*)(Q + ((size_t)row << 9) + (t << 2));
    float s  = v.x + v.y + v.z + v.w;
    float ss = v.x*v.x + v.y*v.y + v.z*v.z + v.w*v.w;
    int nz = (v.x != 0.f) || (v.y != 0.f) || (v.z != 0.f) || (v.w != 0.f);
    __shared__ float rs[128], rss[128];
    __shared__ int rnz[128];
    rs[t] = s; rss[t] = ss; rnz[t] = nz;
    __syncthreads();
    for (int off = 64; off > 0; off >>= 1) {
        if (t < off) { rs[t] += rs[t+off]; rss[t] += rss[t+off]; rnz[t] |= rnz[t+off]; }
        __syncthreads();
    }
    if (t == 0) {
        float f = rnz[0] ? 1.f : 0.f;
        fmask[row] = f;
        if (f != 0.f) {
            atomicAdd(&stats[I_SUM1 + b], rs[0]);
            atomicAdd(&stats[I_SS1 + b], rss[0]);
            atomicAdd(&stats[I_CNT + b], 1.f);
        }
    }
}

// ---------------- stats pass 2: masked sum/sumsq of attn_out ----------------
__global__ __launch_bounds__(128) void stats2_k(const float* __restrict__ X,
                                                const float* __restrict__ fmask,
                                                float* __restrict__ stats) {
    int row = blockIdx.x;
    int b = row >> 10;
    int t = threadIdx.x;
    float f = fmask[row];
    float4 v = *(const float4*)(X + ((size_t)row << 9) + (t << 2));
    float s  = (v.x + v.y + v.z + v.w) * f;
    float ss = (v.x*v.x + v.y*v.y + v.z*v.z + v.w*v.w) * f;
    __shared__ float rs[128], rss[128];
    rs[t] = s; rss[t] = ss;
    __syncthreads();
    for (int off = 64; off > 0; off >>= 1) {
        if (t < off) { rs[t] += rs[t+off]; rss[t] += rss[t+off]; }
        __syncthreads();
    }
    if (t == 0 && f != 0.f) {
        atomicAdd(&stats[I_SUM2 + b], rs[0]);
        atomicAdd(&stats[I_SS2 + b], rss[0]);
    }
}

__global__ void finalize_k(float* __restrict__ stats, int osum, int oss, int ocnt,
                           int omean, int oinv) {
    int b = threadIdx.x;
    if (b < BB) {
        float cntD = stats[ocnt + b] * 512.f;
        float mean = stats[osum + b] / cntD;
        float var  = stats[oss + b] / cntD - mean * mean;
        stats[omean + b] = mean;
        stats[oinv + b]  = rsqrtf(var + EPSV);
    }
}

// ---------------- transpose+cast weights: W[k][n] fp32 -> Wt[n][k] bf16 -----
__global__ __launch_bounds__(256) void tw_k(const float* __restrict__ Wq,
                                            const float* __restrict__ Wk,
                                            const float* __restrict__ Wv,
                                            const float* __restrict__ Wo,
                                            __bf16* __restrict__ Wt) {
    int z = blockIdx.z;
    const float* W = (z == 0) ? Wq : (z == 1) ? Wk : (z == 2) ? Wv : Wo;
    __bf16* dst = Wt + ((size_t)z << 18);
    __shared__ float tile[64][65];
    int t = threadIdx.x;
    int k0 = blockIdx.y << 6, n0 = blockIdx.x << 6;
    int r = t >> 4, c = (t & 15) << 2;
    #pragma unroll
    for (int i = 0; i < 4; ++i) {
        float4 v = *(const float4*)(W + (size_t)(k0 + r + i*16) * 512 + n0 + c);
        tile[r + i*16][c+0] = v.x; tile[r + i*16][c+1] = v.y;
        tile[r + i*16][c+2] = v.z; tile[r + i*16][c+3] = v.w;
    }
    __syncthreads();
    #pragma unroll
    for (int i = 0; i < 4; ++i) {
        int n = r + i*16;
        bf16x4 o;
        o[0] = (__bf16)tile[c+0][n]; o[1] = (__bf16)tile[c+1][n];
        o[2] = (__bf16)tile[c+2][n]; o[3] = (__bf16)tile[c+3][n];
        *(bf16x4*)(dst + (size_t)(n0 + n) * 512 + k0 + c) = o;
    }
}

// ---------------- transpose Vp bf16 [s][h*64+d] -> Vt bf16 [bh][d][s] -------
__global__ __launch_bounds__(256) void tv_k(const __bf16* __restrict__ Vp,
                                            __bf16* __restrict__ Vt) {
    int bh = blockIdx.y; int b = bh >> 3, h = bh & 7;
    int s0 = blockIdx.x << 6;
    __shared__ __bf16 tile[64][68];
    int t = threadIdx.x;
    int r = t >> 4, c = (t & 15) << 2;
    #pragma unroll
    for (int i = 0; i < 4; ++i) {
        bf16x4 v = *(const bf16x4*)(Vp + ((size_t)((b << 10) + s0 + r + i*16) << 9) + (h << 6) + c);
        tile[r + i*16][c+0] = v[0]; tile[r + i*16][c+1] = v[1];
        tile[r + i*16][c+2] = v[2]; tile[r + i*16][c+3] = v[3];
    }
    __syncthreads();
    #pragma unroll
    for (int i = 0; i < 4; ++i) {
        int d = r + i*16;
        bf16x4 o;
        o[0] = tile[c+0][d]; o[1] = tile[c+1][d];
        o[2] = tile[c+2][d]; o[3] = tile[c+3][d];
        *(bf16x4*)(Vt + ((size_t)bh << 16) + ((size_t)d << 10) + s0 + c) = o;
    }
}

// ---------------- fused set_norm + QKV projection (MFMA) --------------------
__global__ __launch_bounds__(256) void proj_gemm(
    const float* __restrict__ Q, const float* __restrict__ stats,
    const float* __restrict__ fmask, const __bf16* __restrict__ Wt,
    const float* __restrict__ bq, const float* __restrict__ bk,
    const float* __restrict__ bv,
    __bf16* __restrict__ Qp, __bf16* __restrict__ Kp, __bf16* __restrict__ Vp)
{
    int z = blockIdx.z;
    const __bf16* W = Wt + ((size_t)z << 18);
    const float* bias = (z == 0) ? bq : (z == 1) ? bk : bv;
    __bf16* C = (z == 0) ? Qp : (z == 1) ? Kp : Vp;
    __shared__ __align__(16) __bf16 smem[64 * LDSTRIDE * 2];
    __bf16* As = smem;
    __bf16* Bs = smem + 64 * LDSTRIDE;
    int t = threadIdx.x;
    int srow = t >> 2, skp = (t & 3) << 3;
    int m0 = blockIdx.y << 6, n0 = blockIdx.x << 6;
    int arow = m0 + srow, ab = arow >> 10;
    float fi   = fmask[arow] * stats[I_INV1 + ab];
    float mean = stats[I_MEAN1 + ab];
    int wave = t >> 6, lane = t & 63, quad = lane >> 4, l16 = lane & 15;
    int aoff  = (wave * 16 + l16) * LDSTRIDE + quad * 8;
    int boff0 = l16 * LDSTRIDE + quad * 8;
    f32x4 acc[4] = {};
    const float*  Arow = Q + ((size_t)arow << 9);
    const __bf16* Brow = W + ((size_t)(n0 + srow) << 9);
    for (int k0 = 0; k0 < 512; k0 += 32) {
        float4 a0 = *(const float4*)(Arow + k0 + skp);
        float4 a1 = *(const float4*)(Arow + k0 + skp + 4);
        bf16x8 av;
        av[0] = (__bf16)((a0.x - mean) * fi); av[1] = (__bf16)((a0.y - mean) * fi);
        av[2] = (__bf16)((a0.z - mean) * fi); av[3] = (__bf16)((a0.w - mean) * fi);
        av[4] = (__bf16)((a1.x - mean) * fi); av[5] = (__bf16)((a1.y - mean) * fi);
        av[6] = (__bf16)((a1.z - mean) * fi); av[7] = (__bf16)((a1.w - mean) * fi);
        *(bf16x8*)&As[srow * LDSTRIDE + skp] = av;
        *(bf16x8*)&Bs[srow * LDSTRIDE + skp] = *(const bf16x8*)(Brow + k0 + skp);
        __syncthreads();
        DO_MFMA();
        __syncthreads();
    }
    // epilogue: stage C tile in LDS (stride 70), then vectorized stores
    __bf16* Cs = smem;     // reuse; safe: all waves past final __syncthreads
    #pragma unroll
    for (int nt = 0; nt < 4; ++nt) {
        int n = n0 + nt * 16 + l16;
        float bn = bias[n];
        #pragma unroll
        for (int reg = 0; reg < 4; ++reg) {
            int m = wave * 16 + quad * 4 + reg;
            float fm = fmask[m0 + m];
            Cs[m * 70 + nt * 16 + l16] = (__bf16)((acc[nt][reg] + bn) * fm);
        }
    }
    __syncthreads();
    int m = t >> 2, ch = (t & 3) << 4;
    bf16x8 o0 = *(const bf16x8*)&Cs[m * 70 + ch];
    bf16x8 o1 = *(const bf16x8*)&Cs[m * 70 + ch + 8];
    *(bf16x8*)(C + ((size_t)(m0 + m) << 9) + n0 + ch)     = o0;
    *(bf16x8*)(C + ((size_t)(m0 + m) << 9) + n0 + ch + 8) = o1;
}

// ---------------- rowsum pre-pass: invrow = fq / sum_k(fk * exp(s*scale)) ---
__global__ __launch_bounds__(256) void rowsum_k(
    const __bf16* __restrict__ Qp, const __bf16* __restrict__ Kp,
    const float* __restrict__ fmask, float* __restrict__ invrow)
{
    int bh = blockIdx.y, b = bh >> 3, h = bh & 7;
    int q0 = blockIdx.x << 6;
    __shared__ __align__(16) __bf16 Qs[64 * ASTR];
    __shared__ __align__(16) __bf16 Ks[64 * ASTR];
    int t = threadIdx.x;
    int wave = t >> 6, lane = t & 63, quad = lane >> 4, l16 = lane & 15;
    int fb = b << 10;
    // stage Q tile once
    #pragma unroll
    for (int it = 0; it < 2; ++it) {
        int row = it * 32 + (t >> 3), c8 = (t & 7) << 3;
        *(bf16x8*)&Qs[row * ASTR + c8] =
            *(const bf16x8*)(Qp + ((size_t)(fb + q0 + row) << 9) + (h << 6) + c8);
    }
    __syncthreads();
    int aoff = (wave * 16 + l16) * ASTR + quad * 8;
    bf16x8 qa0 = *(const bf16x8*)&Qs[aoff];
    bf16x8 qa1 = *(const bf16x8*)&Qs[aoff + 32];
    float rsum[4] = {0.f, 0.f, 0.f, 0.f};
    for (int kc0 = 0; kc0 < 1024; kc0 += 64) {
        #pragma unroll
        for (int it = 0; it < 2; ++it) {
            int row = it * 32 + (t >> 3), c8 = (t & 7) << 3;
            *(bf16x8*)&Ks[row * ASTR + c8] =
                *(const bf16x8*)(Kp + ((size_t)(fb + kc0 + row) << 9) + (h << 6) + c8);
        }
        __syncthreads();
        #pragma unroll
        for (int nt = 0; nt < 4; ++nt) {
            int boff = (nt * 16 + l16) * ASTR + quad * 8;
            f32x4 s = {};
            s = MFMA16(qa0, *(const bf16x8*)&Ks[boff], s);
            s = MFMA16(qa1, *(const bf16x8*)&Ks[boff + 32], s);
            float fk = fmask[fb + kc0 + nt * 16 + l16];
            #pragma unroll
            for (int r = 0; r < 4; ++r)
                rsum[r] += (fk != 0.f) ? __expf(s[r] * SCALE_V) : 0.f;
        }
        __syncthreads();
    }
    #pragma unroll
    for (int r = 0; r < 4; ++r) {
        float v = rsum[r];
        v += __shfl_xor(v, 1); v += __shfl_xor(v, 2);
        v += __shfl_xor(v, 4); v += __shfl_xor(v, 8);
        if (l16 == 0) {
            int q = q0 + wave * 16 + quad * 4 + r;
            float fq = fmask[fb + q];
            invrow[(bh << 10) + q] = (fq != 0.f && v > 0.f) ? 1.f / v : 0.f;
        }
    }
}

// ---------------- fused attention: w (normalized, written once) + attn ------
__global__ __launch_bounds__(256) void attn_k(
    const __bf16* __restrict__ Qp, const __bf16* __restrict__ Kp,
    const __bf16* __restrict__ Vt, const float* __restrict__ invrow,
    const float* __restrict__ fmask, const float* __restrict__ Q,
    float* __restrict__ w, float* __restrict__ attn)
{
    int bh = blockIdx.y, b = bh >> 3, h = bh & 7;
    int q0 = blockIdx.x << 6;
    __shared__ __align__(16) __bf16 Qs[64 * ASTR];
    __shared__ __align__(16) __bf16 Ks[64 * ASTR];
    __shared__ __align__(16) __bf16 Vs[64 * ASTR];
    __shared__ __align__(16) __bf16 Ws[64 * ASTR];
    int t = threadIdx.x;
    int wave = t >> 6, lane = t & 63, quad = lane >> 4, l16 = lane & 15;
    int fb = b << 10;
    #pragma unroll
    for (int it = 0; it < 2; ++it) {
        int row = it * 32 + (t >> 3), c8 = (t & 7) << 3;
        *(bf16x8*)&Qs[row * ASTR + c8] =
            *(const bf16x8*)(Qp + ((size_t)(fb + q0 + row) << 9) + (h << 6) + c8);
    }
    __syncthreads();
    int aoff = (wave * 16 + l16) * ASTR + quad * 8;
    bf16x8 qa0 = *(const bf16x8*)&Qs[aoff];
    bf16x8 qa1 = *(const bf16x8*)&Qs[aoff + 32];
    float inv[4];
    #pragma unroll
    for (int r = 0; r < 4; ++r)
        inv[r] = invrow[(bh << 10) + q0 + wave * 16 + quad * 4 + r];
    f32x4 accO[4] = {};
    size_t wqbase = ((size_t)bh << 20) + ((size_t)q0 << 10);
    for (int kc0 = 0; kc0 < 1024; kc0 += 64) {
        // stage K (rows=kc, cols=d) and V^T (rows=d, cols=kc)
        #pragma unroll
        for (int it = 0; it < 2; ++it) {
            int row = it * 32 + (t >> 3), c8 = (t & 7) << 3;
            *(bf16x8*)&Ks[row * ASTR + c8] =
                *(const bf16x8*)(Kp + ((size_t)(fb + kc0 + row) << 9) + (h << 6) + c8);
            *(bf16x8*)&Vs[row * ASTR + c8] =
                *(const bf16x8*)(Vt + ((size_t)bh << 16) + ((size_t)row << 10) + kc0 + c8);
        }
        __syncthreads();
        // S = Q K^T ; p = exp(s*scale) * fk * inv  (already normalized)
        #pragma unroll
        for (int nt = 0; nt < 4; ++nt) {
            int boff = (nt * 16 + l16) * ASTR + quad * 8;
            f32x4 s = {};
            s = MFMA16(qa0, *(const bf16x8*)&Ks[boff], s);
            s = MFMA16(qa1, *(const bf16x8*)&Ks[boff + 32], s);
            float fk = fmask[fb + kc0 + nt * 16 + l16];
            #pragma unroll
            for (int r = 0; r < 4; ++r) {
                float p = (fk != 0.f) ? __expf(s[r] * SCALE_V) * inv[r] : 0.f;
                Ws[(wave * 16 + quad * 4 + r) * ASTR + nt * 16 + l16] = (__bf16)p;
            }
        }
        __syncthreads();
        // PV: A-frags from Ws, B-frags from Vs; O += P V
        bf16x8 pa0 = *(const bf16x8*)&Ws[aoff];
        bf16x8 pa1 = *(const bf16x8*)&Ws[aoff + 32];
        #pragma unroll
        for (int nt = 0; nt < 4; ++nt) {
            int boff = (nt * 16 + l16) * ASTR + quad * 8;
            accO[nt] = MFMA16(pa0, *(const bf16x8*)&Vs[boff], accO[nt]);
            accO[nt] = MFMA16(pa1, *(const bf16x8*)&Vs[boff + 32], accO[nt]);
        }
        // coalesced w store from Ws
        {
            int q = t >> 2, ch = (t & 3) << 4;
            bf16x8 w0 = *(const bf16x8*)&Ws[q * ASTR + ch];
            bf16x8 w1 = *(const bf16x8*)&Ws[q * ASTR + ch + 8];
            float4 f0, f1, f2, f3;
            f0.x = (float)w0[0]; f0.y = (float)w0[1]; f0.z = (float)w0[2]; f0.w = (float)w0[3];
            f1.x = (float)w0[4]; f1.y = (float)w0[5]; f1.z = (float)w0[6]; f1.w = (float)w0[7];
            f2.x = (float)w1[0]; f2.y = (float)w1[1]; f2.z = (float)w1[2]; f2.w = (float)w1[3];
            f3.x = (float)w1[4]; f3.y = (float)w1[5]; f3.z = (float)w1[6]; f3.w = (float)w1[7];
            float* wp = w + wqbase + ((size_t)q << 10) + kc0 + ch;
            *(float4*)(wp)      = f0;
            *(float4*)(wp + 4)  = f1;
            *(float4*)(wp + 8)  = f2;
            *(float4*)(wp + 12) = f3;
        }
        __syncthreads();
    }
    // epilogue: attn = O + Q
    #pragma unroll
    for (int nt = 0; nt < 4; ++nt) {
        int d = nt * 16 + l16;
        #pragma unroll
        for (int r = 0; r < 4; ++r) {
            int q = q0 + wave * 16 + quad * 4 + r;
            size_t off = ((size_t)(fb + q) << 9) + (h << 6) + d;
            attn[off] = accO[nt][r] + Q[off];
        }
    }
}

// ---------------- out = attn + relu(norm2(attn) @ Wo + bo) ------------------
__global__ __launch_bounds__(256) void final_gemm(
    const float* __restrict__ attn, const float* __restrict__ stats,
    const float* __restrict__ fmask, const __bf16* __restrict__ Wot,
    const float* __restrict__ bo, float* __restrict__ out)
{
    __shared__ __align__(16) __bf16 smem[64 * LDSTRIDE * 2];
    __bf16* As = smem;
    __bf16* Bs = smem + 64 * LDSTRIDE;
    int t = threadIdx.x;
    int srow = t >> 2, skp = (t & 3) << 3;
    int m0 = blockIdx.y << 6, n0 = blockIdx.x << 6;
    int arow = m0 + srow, ab = arow >> 10;
    float fi   = fmask[arow] * stats[I_INV2 + ab];
    float mean = stats[I_MEAN2 + ab];
    int wave = t >> 6, lane = t & 63, quad = lane >> 4, l16 = lane & 15;
    int aoff  = (wave * 16 + l16) * LDSTRIDE + quad * 8;
    int boff0 = l16 * LDSTRIDE + quad * 8;
    f32x4 acc[4] = {};
    const float*  Arow = attn + ((size_t)arow << 9);
    const __bf16* Brow = Wot + ((size_t)(n0 + srow) << 9);
    for (int k0 = 0; k0 < 512; k0 += 32) {
        float4 a0 = *(const float4*)(Arow + k0 + skp);
        float4 a1 = *(const float4*)(Arow + k0 + skp + 4);
        bf16x8 av;
        av[0] = (__bf16)((a0.x - mean) * fi); av[1] = (__bf16)((a0.y - mean) * fi);
        av[2] = (__bf16)((a0.z - mean) * fi); av[3] = (__bf16)((a0.w - mean) * fi);
        av[4] = (__bf16)((a1.x - mean) * fi); av[5] = (__bf16)((a1.y - mean) * fi);
        av[6] = (__bf16)((a1.z - mean) * fi); av[7] = (__bf16)((a1.w - mean) * fi);
        *(bf16x8*)&As[srow * LDSTRIDE + skp] = av;
        *(bf16x8*)&Bs[srow * LDSTRIDE + skp] = *(const bf16x8*)(Brow + k0 + skp);
        __syncthreads();
        DO_MFMA();
        __syncthreads();
    }
    #pragma unroll
    for (int nt = 0; nt < 4; ++nt) {
        int n = n0 + nt * 16 + l16;
        float bn = bo[n];
        #pragma unroll
        for (int reg = 0; reg < 4; ++reg) {
            int m = m0 + wave * 16 + quad * 4 + reg;
            size_t off = ((size_t)m << 9) + n;
            out[off] = attn[off] + fmaxf(acc[nt][reg] + bn, 0.f);
        }
    }
}

extern "C" void kernel_launch(void* const* d_in, const int* in_sizes, int n_in,
                              void* d_out, int out_size, void* d_ws, size_t ws_size,
                              hipStream_t stream) {
    const float* Q  = (const float*)d_in[0];
    const float* Wq = (const float*)d_in[1];
    const float* bq = (const float*)d_in[2];
    const float* Wk = (const float*)d_in[3];
    const float* bk = (const float*)d_in[4];
    const float* Wv = (const float*)d_in[5];
    const float* bv = (const float*)d_in[6];
    const float* Wo = (const float*)d_in[7];
    const float* bo = (const float*)d_in[8];
    float* out = (float*)d_out;                       // (B,S,D) = 4194304 floats
    float* w   = out + (size_t)BB * SS * DD;          // (B,H,S,S) = 67108864 floats

    char* ws = (char*)d_ws;
    float* stats  = (float*)ws;                       // 4 KB reserved
    float* fmask  = (float*)(ws + 4096);              // 32 KB
    float* invrow = (float*)(ws + 4096 + 32768);      // 64*1024 fp32 = 256 KB
    __bf16* Wt = (__bf16*)(ws + 299008);              // 4 x 512x512 bf16 = 2 MB
    __bf16* Qp = Wt + ((size_t)4 << 18);              // each 8 MB
    __bf16* Kp = Qp + ((size_t)NROWS * DD);
    __bf16* Vp = Kp + ((size_t)NROWS * DD);
    __bf16* Vt = Vp + ((size_t)NROWS * DD);           // [bh][64][1024] bf16 = 8 MB
    float* attn = (float*)(Vt + ((size_t)NROWS * DD)); // 16 MB fp32

    (void)hipMemsetAsync(stats, 0, 4096, stream);
    stats1_k<<<NROWS, 128, 0, stream>>>(Q, fmask, stats);
    finalize_k<<<1, 64, 0, stream>>>(stats, I_SUM1, I_SS1, I_CNT, I_MEAN1, I_INV1);
    tw_k<<<dim3(8, 8, 4), 256, 0, stream>>>(Wq, Wk, Wv, Wo, Wt);
    proj_gemm<<<dim3(8, 128, 3), 256, 0, stream>>>(Q, stats, fmask, Wt,
                                                   bq, bk, bv, Qp, Kp, Vp);
    tv_k<<<dim3(16, 64), 256, 0, stream>>>(Vp, Vt);
    rowsum_k<<<dim3(16, 64), 256, 0, stream>>>(Qp, Kp, fmask, invrow);
    attn_k<<<dim3(16, 64), 256, 0, stream>>>(Qp, Kp, Vt, invrow, fmask, Q, w, attn);
    stats2_k<<<NROWS, 128, 0, stream>>>(attn, fmask, stats);
    finalize_k<<<1, 64, 0, stream>>>(stats, I_SUM2, I_SS2, I_CNT, I_MEAN2, I_INV2);
    final_gemm<<<dim3(8, 128), 256, 0, stream>>>(attn, stats, fmask,
                                                 Wt + ((size_t)3 << 18), bo, out);
}